// Round 5
// baseline (238.052 us; speedup 1.0000x reference)
//
#include <hip/hip_runtime.h>
#include <hip/hip_bf16.h>
#include <math.h>

#define B_ 8
#define N_ 4096
#define C_ 256
#define DQK_ 32

typedef float f32x4  __attribute__((ext_vector_type(4)));
typedef float f32x16 __attribute__((ext_vector_type(16)));
typedef short bf16x8 __attribute__((ext_vector_type(8)));
typedef short bf16x4 __attribute__((ext_vector_type(4)));

__device__ __forceinline__ short f2bf(float f){
  union { float f; unsigned u; } v; v.f = f;
  unsigned r = v.u + 0x7fffu + ((v.u >> 16) & 1u);
  return (short)(r >> 16);
}

// ---------- kernel 1: weight transpose + cast -> WT[320][256] bf16 ----------
__global__ void cast_wt_kernel(const float* __restrict__ Wq, const float* __restrict__ Wk,
                               const float* __restrict__ Wv, short* __restrict__ WT){
  int n = blockIdx.x;        // 0..319 output channel
  int k = threadIdx.x;       // 0..255 input channel
  float val;
  if (n < 32)       val = Wq[k*32 + n];
  else if (n < 64)  val = Wk[k*32 + (n-32)];
  else              val = Wv[k*256 + (n-64)];
  WT[n*256 + k] = f2bf(val);
}

// ---------- kernel 2: projections -> frag-swizzled q,k,v ----------
__global__ __launch_bounds__(256) void proj_kernel(
    const float* __restrict__ x, const short* __restrict__ WT,
    const float* __restrict__ bq, const float* __restrict__ bk, const float* __restrict__ bv,
    short* __restrict__ qws, short* __restrict__ kws, short* __restrict__ vSw){
  __shared__ __align__(16) short sX[64*264];   // 67584 B
  __shared__ __align__(16) short sT[64*72];    // 9216 B  (q cols 0..31 | k cols 32..63)
  int tid = threadIdx.x;
  int lane = tid & 63, wave = tid >> 6;
  int lane15 = lane & 15, quad = lane >> 4;
  int mbase = blockIdx.x * 64;
  int b = mbase >> 12, kvb = mbase & (N_-1);

  const float* xr = x + (size_t)mbase * C_;
  for (int i = 0; i < 8; i++){
    int s = tid + i*256;
    int row = s >> 5, cg = (s & 31) << 3;
    const f32x4* src = (const f32x4*)(xr + row*C_ + cg);
    f32x4 a = src[0], c = src[1];
    bf16x8 p;
    p[0]=f2bf(a[0]); p[1]=f2bf(a[1]); p[2]=f2bf(a[2]); p[3]=f2bf(a[3]);
    p[4]=f2bf(c[0]); p[5]=f2bf(c[1]); p[6]=f2bf(c[2]); p[7]=f2bf(c[3]);
    *(bf16x8*)(sX + row*264 + cg) = p;
  }
  __syncthreads();

  f32x4 acc[5][4];
  for (int i=0;i<5;i++) for (int mt=0;mt<4;mt++) acc[i][mt] = (f32x4)(0.f);

  for (int kc = 0; kc < 8; kc++){
    bf16x8 afr[4];
    #pragma unroll
    for (int mt=0;mt<4;mt++)
      afr[mt] = *(const bf16x8*)(sX + (mt*16+lane15)*264 + kc*32 + quad*8);
    bf16x8 bfr[5];
    #pragma unroll
    for (int i=0;i<5;i++){
      int t = i*4 + wave;
      bfr[i] = *(const bf16x8*)(WT + (size_t)(t*16+lane15)*256 + kc*32 + quad*8);
    }
    #pragma unroll
    for (int i=0;i<5;i++)
      #pragma unroll
      for (int mt=0;mt<4;mt++)
        acc[i][mt] = __builtin_amdgcn_mfma_f32_16x16x32_bf16(afr[mt], bfr[i], acc[i][mt], 0,0,0);
  }

  #pragma unroll
  for (int i=0;i<5;i++){
    int t = i*4 + wave;
    int n0 = t*16 + lane15;
    float bias = (n0 < 32) ? bq[n0] : (n0 < 64 ? bk[n0-32] : bv[n0-64]);
    if (n0 < 64){
      #pragma unroll
      for (int mt=0;mt<4;mt++)
        #pragma unroll
        for (int r=0;r<4;r++)
          sT[(mt*16 + quad*4 + r)*72 + n0] = f2bf(acc[i][mt][r] + bias);
    } else {
      int ch = n0 - 64, cht = ch >> 5, c5 = ch & 31;
      int lanep = c5 | ((quad & 1) << 5);
      int jo = (quad >> 1) * 4;
      #pragma unroll
      for (int mt=0;mt<4;mt++){
        bf16x4 pk;
        pk[0]=f2bf(acc[i][mt][0]+bias); pk[1]=f2bf(acc[i][mt][1]+bias);
        pk[2]=f2bf(acc[i][mt][2]+bias); pk[3]=f2bf(acc[i][mt][3]+bias);
        size_t off = (size_t)b*1048576 + (size_t)(kvb>>6)*16384
                   + (size_t)(mt*8 + cht)*512 + (size_t)lanep*8 + jo;
        *(bf16x4*)(vSw + off) = pk;
      }
    }
  }
  __syncthreads();

  {
    int qt = tid >> 7, p = (tid >> 6) & 1, ln = tid & 63;
    int row = qt*32 + (ln & 31);
    int dcol = p*16 + (ln >> 5)*8;
    bf16x8 vq = *(const bf16x8*)(sT + row*72 + dcol);
    bf16x8 vk = *(const bf16x8*)(sT + row*72 + 32 + dcol);
    size_t qoff = ((((size_t)b*128 + ((kvb>>5) + qt))*2 + p)*64 + ln)*8;
    *(bf16x8*)(qws + qoff) = vq;
    size_t koff = ((size_t)b*64 + (kvb>>6))*2048 + (size_t)((qt*2 + p)*64 + ln)*8;
    *(bf16x8*)(kws + koff) = vk;
  }
}

// ---------- kernel 3: flash attention + residual (v6: V-reuse + pf exchange) ----------
// Serial-pipe model fit from v1/v3/v5: chunk_cyc = LDS_KB * 12.2 (=85.9 B/cyc, the
// measured ds_read_b128 ceiling) + remainder(VALU/fixed). v5 cut LDS 160->96 KB but
// duplicated exp across cd-pair waves (+1030 cyc VALU, VALUBusy 27->45.5). v6 keeps
// v5's 2x V register-reuse but computes each S piece ONCE (v1's assignment: wave
// (qp,cd,kh) owns tile 2qp+cd, kv-half kh) and EXCHANGES packed P-frags via LDS
// (2 KB write + 2 KB read per wave << 64 KB of V reads saved).
// One barrier per chunk: pf exchange is pipelined one chunk ahead (QK(t+1)+exp(t+1)
// computed during chunk t from reg-resident K; pfX double-buffered by chunk parity;
// the end-of-chunk barrier orders pf(t+1) writes vs next chunk's reads).
// Ledger vs v1: LDS 160->128 KB/chunk (stage 32 + V 64 + pf 32), exp single-counted,
// MFMA 160->144 (no ones-rowsum; rowsum = VALU adds, validated v4/v5).
// Regs: acc 8xf32x16=128 + own-tile Q 16 + kfc 16 + pfO/pfN/pfP 48 + misc ~35 <= 256.
__global__ __launch_bounds__(512, 2) void flash_kernel(
    const float* __restrict__ x, const short* __restrict__ qws, const short* __restrict__ kws,
    const short* __restrict__ vSw, const float* __restrict__ gptr, float* __restrict__ out){
  __shared__ __align__(16) char smem[98304];   // sV[2] 64KB + pfX[2] 32KB; epi: R 64KB + RS 1KB
  short* sV0 = (short*)smem;
  short* sV1 = (short*)(smem + 32768);
  short* pfX = (short*)(smem + 65536);         // [buf2][wave8][frag2][lane64][8] = 32 KB
  int tid = threadIdx.x;
  int lane = tid & 63, wave = tid >> 6;        // wave 0..7
  int l31 = lane & 31, h = lane >> 5;
  int qp = wave >> 2, cd = (wave >> 1) & 1, kh = wave & 1;
  int b = blockIdx.x & 7;
  int q0 = (blockIdx.x >> 3) << 7;             // 128 q-rows per block

  const short* qb = qws + (size_t)b*131072;
  const short* kb = kws + (size_t)b*131072;
  const short* vb = vSw + (size_t)b*1048576;

  // own S tile: 2qp+cd (each S piece computed by exactly one wave)
  int qtg = (q0 >> 5) + qp*2 + cd;
  bf16x8 qf0 = *(const bf16x8*)(qb + (size_t)((qtg*2+0)*64 + lane)*8);
  bf16x8 qf1 = *(const bf16x8*)(qb + (size_t)((qtg*2+1)*64 + lane)*8);

  const short* kf0p = kb + (size_t)((2*kh+0)*64 + lane)*8;
  const short* kf1p = kb + (size_t)((2*kh+1)*64 + lane)*8;
  bf16x8 kfc0 = *(const bf16x8*)(kf0p);        // K(0); reloaded in-place each chunk
  bf16x8 kfc1 = *(const bf16x8*)(kf1p);

#define VPREF(CHUNK, DST) do { \
    const short* vsrc_ = vb + (size_t)(CHUNK)*16384; \
    _Pragma("unroll") \
    for (int r_=0;r_<4;r_++) \
      __builtin_amdgcn_global_load_lds( \
        (const __attribute__((address_space(1))) void*)(vsrc_ + (size_t)(r_*512+tid)*8), \
        (__attribute__((address_space(3))) void*)((DST) + (size_t)(r_*512+tid)*8), 16, 0, 0); \
  } while(0)

#define EXPPACK(S, PF) do { \
    float ls_ = 0.f; \
    _Pragma("unroll") \
    for (int g_=0; g_<2; g_++){ \
      union { bf16x8 v; unsigned u[4]; } P_; \
      _Pragma("unroll") \
      for (int j_=0;j_<4;j_++){ \
        float2 e_; \
        e_.x = __expf((S)[g_*8 + 2*j_]); \
        e_.y = __expf((S)[g_*8 + 2*j_ + 1]); \
        ls_ += e_.x + e_.y; \
        __hip_bfloat162 t2_ = __float22bfloat162_rn(e_); \
        __builtin_memcpy(&P_.u[j_], &t2_, 4); \
      } \
      (PF)[g_] = P_.v; \
    } \
    rsO += ls_; \
  } while(0)

// PV: PA feeds accA (tile 2qp), PB feeds accB (tile 2qp+1); V frag read once, used twice
#define PVX(SVC, PA, PB) do { \
    _Pragma("unroll") \
    for (int ks_=0; ks_<2; ks_++){ \
      const short* base_ = (SVC) + (2*kh + ks_)*4096; \
      _Pragma("unroll") \
      for (int c_=0; c_<4; c_++){ \
        bf16x8 vf_ = *(const bf16x8*)(base_ + ((cd*4+c_)*64 + lane)*8); \
        accA[c_] = __builtin_amdgcn_mfma_f32_32x32x16_bf16((PA)[ks_], vf_, accA[c_], 0,0,0); \
        accB[c_] = __builtin_amdgcn_mfma_f32_32x32x16_bf16((PB)[ks_], vf_, accB[c_], 0,0,0); \
      } \
    } \
  } while(0)

  VPREF(0, sV0);

  f32x16 accA[4], accB[4];
  #pragma unroll
  for (int t=0;t<4;t++){ accA[t] = (f32x16)(0.f); accB[t] = (f32x16)(0.f); }
  float rsO = 0.f;
  bf16x8 pfO[2];

  // prologue: pf(0) from K(0); publish to pfX buf0; reload kfc <- K(1)
  {
    f32x16 s = __builtin_amdgcn_mfma_f32_32x32x16_bf16(kfc0, qf0, (f32x16)(0.f), 0,0,0);
    s        = __builtin_amdgcn_mfma_f32_32x32x16_bf16(kfc1, qf1, s, 0,0,0);
    EXPPACK(s, pfO);
    *(bf16x8*)(pfX + ((0*8 + wave)*2 + 0)*512 + lane*8) = pfO[0];
    *(bf16x8*)(pfX + ((0*8 + wave)*2 + 1)*512 + lane*8) = pfO[1];
  }
  kfc0 = *(const bf16x8*)(kf0p + 2048);
  kfc1 = *(const bf16x8*)(kf1p + 2048);
  __syncthreads();                             // stage(0) + pf(0) exchange ready

  for (int it=0; it<64; it++){
    short* sVc = (it & 1) ? sV1 : sV0;
    short* sVn = (it & 1) ? sV0 : sV1;
    if (it < 63) VPREF(it+1, sVn);

    // QK(t+1) + exp(t+1) from reg-resident K(t+1); publish pf(t+1) to other pfX buf
    bf16x8 pfN[2];
    if (it < 63){
      f32x16 s = __builtin_amdgcn_mfma_f32_32x32x16_bf16(kfc0, qf0, (f32x16)(0.f), 0,0,0);
      s        = __builtin_amdgcn_mfma_f32_32x32x16_bf16(kfc1, qf1, s, 0,0,0);
      EXPPACK(s, pfN);
      *(bf16x8*)(pfX + ((((it+1)&1)*8 + wave)*2 + 0)*512 + lane*8) = pfN[0];
      *(bf16x8*)(pfX + ((((it+1)&1)*8 + wave)*2 + 1)*512 + lane*8) = pfN[1];
    }
    if (it < 62){
      kfc0 = *(const bf16x8*)(kf0p + (size_t)(it+2)*2048);
      kfc1 = *(const bf16x8*)(kf1p + (size_t)(it+2)*2048);
    }

    // partner's pf(t) (published last chunk; ordered by the end-of-chunk barrier)
    bf16x8 pfP[2];
    pfP[0] = *(const bf16x8*)(pfX + (((it&1)*8 + (wave^2))*2 + 0)*512 + lane*8);
    pfP[1] = *(const bf16x8*)(pfX + (((it&1)*8 + (wave^2))*2 + 1)*512 + lane*8);

    if (cd == 0){ PVX(sVc, pfO, pfP); }        // own tile = A (2qp)
    else        { PVX(sVc, pfP, pfO); }        // own tile = B (2qp+1)

    if (it < 63){ pfO[0] = pfN[0]; pfO[1] = pfN[1]; }
    __syncthreads();
  }

  // ---- rowsum: merge h-interleaved kv rows; each wave publishes its own piece ----
  rsO += __shfl_xor(rsO, 32);
  float* R  = (float*)smem;                    // [wave][j(2)][i(16)][lane] = 64 KB
  float* RS = (float*)(smem + 65536);          // [wave][32] = 1 KB (aliases dead pfX)
  int pw = wave ^ 1;                           // partner: same (qp,cd), other kh
  if (lane < 32) RS[wave*32 + l31] = rsO;

  // ---- cross-kh merge: kh0 keeps tile A, kh1 keeps tile B; give the other ----
  // phase 1: accs 0,1 of give tile
  if (kh == 0){
    #pragma unroll
    for (int i=0;i<16;i++){ R[wave*2048 + i*64 + lane] = accB[0][i];
                            R[wave*2048 + 1024 + i*64 + lane] = accB[1][i]; }
  } else {
    #pragma unroll
    for (int i=0;i<16;i++){ R[wave*2048 + i*64 + lane] = accA[0][i];
                            R[wave*2048 + 1024 + i*64 + lane] = accA[1][i]; }
  }
  __syncthreads();
  if (kh == 0){
    #pragma unroll
    for (int i=0;i<16;i++){ accA[0][i] += R[pw*2048 + i*64 + lane];
                            accA[1][i] += R[pw*2048 + 1024 + i*64 + lane]; }
  } else {
    #pragma unroll
    for (int i=0;i<16;i++){ accB[0][i] += R[pw*2048 + i*64 + lane];
                            accB[1][i] += R[pw*2048 + 1024 + i*64 + lane]; }
  }
  __syncthreads();
  // phase 2: accs 2,3 of give tile
  if (kh == 0){
    #pragma unroll
    for (int i=0;i<16;i++){ R[wave*2048 + i*64 + lane] = accB[2][i];
                            R[wave*2048 + 1024 + i*64 + lane] = accB[3][i]; }
  } else {
    #pragma unroll
    for (int i=0;i<16;i++){ R[wave*2048 + i*64 + lane] = accA[2][i];
                            R[wave*2048 + 1024 + i*64 + lane] = accA[3][i]; }
  }
  __syncthreads();
  if (kh == 0){
    #pragma unroll
    for (int i=0;i<16;i++){ accA[2][i] += R[pw*2048 + i*64 + lane];
                            accA[3][i] += R[pw*2048 + 1024 + i*64 + lane]; }
  } else {
    #pragma unroll
    for (int i=0;i<16;i++){ accB[2][i] += R[pw*2048 + i*64 + lane];
                            accB[3][i] += R[pw*2048 + 1024 + i*64 + lane]; }
  }

  // ---- epilogue: out = gamma*O/l + x ----
  // wave writes tile kt = 2qp+kh, channels [cd*128, +128)
  // rowsum of tile kt = RS[wave computed (kt,kh'=0)] + RS[(kt,kh'=1)]
  //                   = RS[qp*4 + kh*2 + 0] + RS[qp*4 + kh*2 + 1]
  float g = *gptr;
  int kt = qp*2 + kh;
  int w0 = qp*4 + kh*2, w1 = w0 + 1;
  const float* xb = x + ((size_t)b*N_ + q0 + kt*32)*C_;
  float*       ob = out + ((size_t)b*N_ + q0 + kt*32)*C_;
  if (kh == 0){
    #pragma unroll
    for (int i=0;i<16;i++){
      int q = (i&3) + 8*(i>>2) + 4*h;
      float rv = 1.f / (RS[w0*32 + q] + RS[w1*32 + q]);
      #pragma unroll
      for (int c=0;c<4;c++){
        int ch = (cd*4 + c)*32 + l31;
        ob[(size_t)q*C_ + ch] = g*(accA[c][i]*rv) + xb[(size_t)q*C_ + ch];
      }
    }
  } else {
    #pragma unroll
    for (int i=0;i<16;i++){
      int q = (i&3) + 8*(i>>2) + 4*h;
      float rv = 1.f / (RS[w0*32 + q] + RS[w1*32 + q]);
      #pragma unroll
      for (int c=0;c<4;c++){
        int ch = (cd*4 + c)*32 + l31;
        ob[(size_t)q*C_ + ch] = g*(accB[c][i]*rv) + xb[(size_t)q*C_ + ch];
      }
    }
  }
#undef VPREF
#undef EXPPACK
#undef PVX
}

extern "C" void kernel_launch(void* const* d_in, const int* in_sizes, int n_in,
                              void* d_out, int out_size, void* d_ws, size_t ws_size,
                              hipStream_t stream){
  const float* x  = (const float*)d_in[0];
  const float* Wq = (const float*)d_in[1];
  const float* bq = (const float*)d_in[2];
  const float* Wk = (const float*)d_in[3];
  const float* bk = (const float*)d_in[4];
  const float* Wv = (const float*)d_in[5];
  const float* bv = (const float*)d_in[6];
  const float* gm = (const float*)d_in[7];
  float* out = (float*)d_out;
  char* ws = (char*)d_ws;
  short* WT  = (short*)ws;                               // 163840 B
  short* qws = (short*)(ws + 163840);                    // 2097152 B
  short* kws = (short*)(ws + 163840 + 2097152);          // 2097152 B
  short* vSw = (short*)(ws + 163840 + 2*2097152);        // 16777216 B

  cast_wt_kernel<<<dim3(320), dim3(256), 0, stream>>>(Wq, Wk, Wv, WT);
  proj_kernel<<<dim3(512), dim3(256), 0, stream>>>(x, WT, bq, bk, bv, qws, kws, vSw);
  flash_kernel<<<dim3(256), dim3(512), 0, stream>>>(x, qws, kws, vSw, gm, out);
}

// Round 6
// 205.140 us; speedup vs baseline: 1.1604x; 1.1604x over previous
//
#include <hip/hip_runtime.h>
#include <hip/hip_bf16.h>
#include <math.h>

#define B_ 8
#define N_ 4096
#define C_ 256
#define DQK_ 32

typedef float f32x4  __attribute__((ext_vector_type(4)));
typedef float f32x16 __attribute__((ext_vector_type(16)));
typedef short bf16x8 __attribute__((ext_vector_type(8)));
typedef short bf16x4 __attribute__((ext_vector_type(4)));

__device__ __forceinline__ short f2bf(float f){
  union { float f; unsigned u; } v; v.f = f;
  unsigned r = v.u + 0x7fffu + ((v.u >> 16) & 1u);
  return (short)(r >> 16);
}

// ---------- kernel 1: weight transpose + cast -> WT[320][256] bf16 ----------
__global__ void cast_wt_kernel(const float* __restrict__ Wq, const float* __restrict__ Wk,
                               const float* __restrict__ Wv, short* __restrict__ WT){
  int n = blockIdx.x;        // 0..319 output channel
  int k = threadIdx.x;       // 0..255 input channel
  float val;
  if (n < 32)       val = Wq[k*32 + n];
  else if (n < 64)  val = Wk[k*32 + (n-32)];
  else              val = Wv[k*256 + (n-64)];
  WT[n*256 + k] = f2bf(val);
}

// ---------- kernel 2: projections -> frag-swizzled q,k,v ----------
__global__ __launch_bounds__(256) void proj_kernel(
    const float* __restrict__ x, const short* __restrict__ WT,
    const float* __restrict__ bq, const float* __restrict__ bk, const float* __restrict__ bv,
    short* __restrict__ qws, short* __restrict__ kws, short* __restrict__ vSw){
  __shared__ __align__(16) short sX[64*264];   // 67584 B
  __shared__ __align__(16) short sT[64*72];    // 9216 B  (q cols 0..31 | k cols 32..63)
  int tid = threadIdx.x;
  int lane = tid & 63, wave = tid >> 6;
  int lane15 = lane & 15, quad = lane >> 4;
  int mbase = blockIdx.x * 64;
  int b = mbase >> 12, kvb = mbase & (N_-1);

  const float* xr = x + (size_t)mbase * C_;
  for (int i = 0; i < 8; i++){
    int s = tid + i*256;
    int row = s >> 5, cg = (s & 31) << 3;
    const f32x4* src = (const f32x4*)(xr + row*C_ + cg);
    f32x4 a = src[0], c = src[1];
    bf16x8 p;
    p[0]=f2bf(a[0]); p[1]=f2bf(a[1]); p[2]=f2bf(a[2]); p[3]=f2bf(a[3]);
    p[4]=f2bf(c[0]); p[5]=f2bf(c[1]); p[6]=f2bf(c[2]); p[7]=f2bf(c[3]);
    *(bf16x8*)(sX + row*264 + cg) = p;
  }
  __syncthreads();

  f32x4 acc[5][4];
  for (int i=0;i<5;i++) for (int mt=0;mt<4;mt++) acc[i][mt] = (f32x4)(0.f);

  for (int kc = 0; kc < 8; kc++){
    bf16x8 afr[4];
    #pragma unroll
    for (int mt=0;mt<4;mt++)
      afr[mt] = *(const bf16x8*)(sX + (mt*16+lane15)*264 + kc*32 + quad*8);
    bf16x8 bfr[5];
    #pragma unroll
    for (int i=0;i<5;i++){
      int t = i*4 + wave;
      bfr[i] = *(const bf16x8*)(WT + (size_t)(t*16+lane15)*256 + kc*32 + quad*8);
    }
    #pragma unroll
    for (int i=0;i<5;i++)
      #pragma unroll
      for (int mt=0;mt<4;mt++)
        acc[i][mt] = __builtin_amdgcn_mfma_f32_16x16x32_bf16(afr[mt], bfr[i], acc[i][mt], 0,0,0);
  }

  #pragma unroll
  for (int i=0;i<5;i++){
    int t = i*4 + wave;
    int n0 = t*16 + lane15;
    float bias = (n0 < 32) ? bq[n0] : (n0 < 64 ? bk[n0-32] : bv[n0-64]);
    if (n0 < 64){
      #pragma unroll
      for (int mt=0;mt<4;mt++)
        #pragma unroll
        for (int r=0;r<4;r++)
          sT[(mt*16 + quad*4 + r)*72 + n0] = f2bf(acc[i][mt][r] + bias);
    } else {
      int ch = n0 - 64, cht = ch >> 5, c5 = ch & 31;
      int lanep = c5 | ((quad & 1) << 5);
      int jo = (quad >> 1) * 4;
      #pragma unroll
      for (int mt=0;mt<4;mt++){
        bf16x4 pk;
        pk[0]=f2bf(acc[i][mt][0]+bias); pk[1]=f2bf(acc[i][mt][1]+bias);
        pk[2]=f2bf(acc[i][mt][2]+bias); pk[3]=f2bf(acc[i][mt][3]+bias);
        size_t off = (size_t)b*1048576 + (size_t)(kvb>>6)*16384
                   + (size_t)(mt*8 + cht)*512 + (size_t)lanep*8 + jo;
        *(bf16x4*)(vSw + off) = pk;
      }
    }
  }
  __syncthreads();

  {
    int qt = tid >> 7, p = (tid >> 6) & 1, ln = tid & 63;
    int row = qt*32 + (ln & 31);
    int dcol = p*16 + (ln >> 5)*8;
    bf16x8 vq = *(const bf16x8*)(sT + row*72 + dcol);
    bf16x8 vk = *(const bf16x8*)(sT + row*72 + 32 + dcol);
    size_t qoff = ((((size_t)b*128 + ((kvb>>5) + qt))*2 + p)*64 + ln)*8;
    *(bf16x8*)(qws + qoff) = vq;
    size_t koff = ((size_t)b*64 + (kvb>>6))*2048 + (size_t)((qt*2 + p)*64 + ln)*8;
    *(bf16x8*)(kws + koff) = vk;
  }
}

// ---------- kernel 3: flash attention + residual (v7: pf exchange, 2-barrier-lite) ----------
// Model (fit v1/v3/v5): chunk_cyc = LDS_KB*12.2 + remainder. v6 proved the pf-exchange
// correctness but spilled (cross-chunk pipeline pushed regs past 256 -> +120MB scratch).
// v7 drops the cross-chunk pf state entirely:
//   per chunk: QK(t)+exp(t) -> publish own pf to pfX (single 16KB buffer) ->
//   RAW s_barrier (lgkmcnt(0) drain only; NO vmcnt drain, so chunk-(t+1) V staging
//   issued at chunk top stays in flight across it; rule #18 sched_barrier fencing) ->
//   read partner pf -> PV with own+partner -> __syncthreads (orders staging + pfX reuse).
// Ledger vs v1: LDS 160->128 KB/chunk (stage 32 + V 64 + pf 32); exp single-counted;
// MFMA 160->144/chunk/CU. Regs: acc 128 AGPR + Q 16 + kfc 16 + pfO 16 + pfP 16 +
// transients ~110 VGPR -> ~238 < 248 (v5's proven fit). Wave (qp,cd,kh): owns S tile
// 2qp+cd, kv-half kh; PV covers tiles {2qp,2qp+1} x ch [cd*128,+128) x kv-half kh.
__global__ __launch_bounds__(512, 2) void flash_kernel(
    const float* __restrict__ x, const short* __restrict__ qws, const short* __restrict__ kws,
    const short* __restrict__ vSw, const float* __restrict__ gptr, float* __restrict__ out){
  __shared__ __align__(16) char smem[81920];   // sV[2] 64KB + pfX 16KB; epi: R 64KB + RS 1KB
  short* sV0 = (short*)smem;
  short* sV1 = (short*)(smem + 32768);
  short* pfX = (short*)(smem + 65536);         // [wave8][frag2][lane64][8] = 16 KB
  int tid = threadIdx.x;
  int lane = tid & 63, wave = tid >> 6;        // wave 0..7
  int l31 = lane & 31, h = lane >> 5;
  int qp = wave >> 2, cd = (wave >> 1) & 1, kh = wave & 1;
  int b = blockIdx.x & 7;
  int q0 = (blockIdx.x >> 3) << 7;             // 128 q-rows per block

  const short* qb = qws + (size_t)b*131072;
  const short* kb = kws + (size_t)b*131072;
  const short* vb = vSw + (size_t)b*1048576;

  // own S tile: 2qp+cd (each S piece computed by exactly one wave)
  int qtg = (q0 >> 5) + qp*2 + cd;
  bf16x8 qf0 = *(const bf16x8*)(qb + (size_t)((qtg*2+0)*64 + lane)*8);
  bf16x8 qf1 = *(const bf16x8*)(qb + (size_t)((qtg*2+1)*64 + lane)*8);

  const short* kf0p = kb + (size_t)((2*kh+0)*64 + lane)*8;
  const short* kf1p = kb + (size_t)((2*kh+1)*64 + lane)*8;
  bf16x8 kfc0 = *(const bf16x8*)(kf0p);        // K(0); reloaded in-place each chunk
  bf16x8 kfc1 = *(const bf16x8*)(kf1p);

#define VPREF(CHUNK, DST) do { \
    const short* vsrc_ = vb + (size_t)(CHUNK)*16384; \
    _Pragma("unroll") \
    for (int r_=0;r_<4;r_++) \
      __builtin_amdgcn_global_load_lds( \
        (const __attribute__((address_space(1))) void*)(vsrc_ + (size_t)(r_*512+tid)*8), \
        (__attribute__((address_space(3))) void*)((DST) + (size_t)(r_*512+tid)*8), 16, 0, 0); \
  } while(0)

#define EXPPACK(S, PF) do { \
    float ls_ = 0.f; \
    _Pragma("unroll") \
    for (int g_=0; g_<2; g_++){ \
      union { bf16x8 v; unsigned u[4]; } P_; \
      _Pragma("unroll") \
      for (int j_=0;j_<4;j_++){ \
        float2 e_; \
        e_.x = __expf((S)[g_*8 + 2*j_]); \
        e_.y = __expf((S)[g_*8 + 2*j_ + 1]); \
        ls_ += e_.x + e_.y; \
        __hip_bfloat162 t2_ = __float22bfloat162_rn(e_); \
        __builtin_memcpy(&P_.u[j_], &t2_, 4); \
      } \
      (PF)[g_] = P_.v; \
    } \
    rsO += ls_; \
  } while(0)

// PV: PA feeds accA (tile 2qp), PB feeds accB (tile 2qp+1); V frag read once, used twice
#define PVX(SVC, PA, PB) do { \
    _Pragma("unroll") \
    for (int ks_=0; ks_<2; ks_++){ \
      const short* base_ = (SVC) + (2*kh + ks_)*4096; \
      _Pragma("unroll") \
      for (int c_=0; c_<4; c_++){ \
        bf16x8 vf_ = *(const bf16x8*)(base_ + ((cd*4+c_)*64 + lane)*8); \
        accA[c_] = __builtin_amdgcn_mfma_f32_32x32x16_bf16((PA)[ks_], vf_, accA[c_], 0,0,0); \
        accB[c_] = __builtin_amdgcn_mfma_f32_32x32x16_bf16((PB)[ks_], vf_, accB[c_], 0,0,0); \
      } \
    } \
  } while(0)

  VPREF(0, sV0);

  f32x16 accA[4], accB[4];
  #pragma unroll
  for (int t=0;t<4;t++){ accA[t] = (f32x16)(0.f); accB[t] = (f32x16)(0.f); }
  float rsO = 0.f;

  __syncthreads();                             // stage(0) complete (vmcnt drain)

  for (int it=0; it<64; it++){
    short* sVc = (it & 1) ? sV1 : sV0;
    short* sVn = (it & 1) ? sV0 : sV1;
    if (it < 63) VPREF(it+1, sVn);             // in flight across the raw barrier below

    // QK(t) + exp(t) from reg-resident K(t)
    bf16x8 pfO[2];
    {
      f32x16 s = __builtin_amdgcn_mfma_f32_32x32x16_bf16(kfc0, qf0, (f32x16)(0.f), 0,0,0);
      s        = __builtin_amdgcn_mfma_f32_32x32x16_bf16(kfc1, qf1, s, 0,0,0);
      EXPPACK(s, pfO);
    }
    // publish own pf (16B/lane contiguous -> conflict-free)
    *(bf16x8*)(pfX + ((size_t)wave*2 + 0)*512 + lane*8) = pfO[0];
    *(bf16x8*)(pfX + ((size_t)wave*2 + 1)*512 + lane*8) = pfO[1];
    // kfc dead after QK -> reload in place for next chunk (vmcnt, not lgkm; overlaps)
    if (it < 63){
      kfc0 = *(const bf16x8*)(kf0p + (size_t)(it+1)*2048);
      kfc1 = *(const bf16x8*)(kf1p + (size_t)(it+1)*2048);
    }

    // pf-exchange barrier: drain ds_writes only; raw s_barrier keeps staging in flight.
    asm volatile("s_waitcnt lgkmcnt(0)" ::: "memory");
    __builtin_amdgcn_sched_barrier(0);
    __builtin_amdgcn_s_barrier();
    __builtin_amdgcn_sched_barrier(0);

    // partner's pf (wave^2 = same qp,kh, other cd)
    bf16x8 pfP[2];
    pfP[0] = *(const bf16x8*)(pfX + ((size_t)(wave^2)*2 + 0)*512 + lane*8);
    pfP[1] = *(const bf16x8*)(pfX + ((size_t)(wave^2)*2 + 1)*512 + lane*8);

    if (cd == 0){ PVX(sVc, pfO, pfP); }        // own tile = A (2qp)
    else        { PVX(sVc, pfP, pfO); }        // own tile = B (2qp+1)

    __syncthreads();                           // orders sVn staging + pfX reuse
  }

  // ---- rowsum: merge h-interleaved kv rows; each wave publishes its own piece ----
  rsO += __shfl_xor(rsO, 32);
  float* R  = (float*)smem;                    // [wave][j(2)][i(16)][lane] = 64 KB
  float* RS = (float*)(smem + 65536);          // [wave][32] = 1 KB (aliases dead pfX)
  int pw = wave ^ 1;                           // partner: same (qp,cd), other kh
  if (lane < 32) RS[wave*32 + l31] = rsO;

  // ---- cross-kh merge: kh0 keeps tile A, kh1 keeps tile B; give the other ----
  // phase 1: accs 0,1 of give tile
  if (kh == 0){
    #pragma unroll
    for (int i=0;i<16;i++){ R[wave*2048 + i*64 + lane] = accB[0][i];
                            R[wave*2048 + 1024 + i*64 + lane] = accB[1][i]; }
  } else {
    #pragma unroll
    for (int i=0;i<16;i++){ R[wave*2048 + i*64 + lane] = accA[0][i];
                            R[wave*2048 + 1024 + i*64 + lane] = accA[1][i]; }
  }
  __syncthreads();
  if (kh == 0){
    #pragma unroll
    for (int i=0;i<16;i++){ accA[0][i] += R[pw*2048 + i*64 + lane];
                            accA[1][i] += R[pw*2048 + 1024 + i*64 + lane]; }
  } else {
    #pragma unroll
    for (int i=0;i<16;i++){ accB[0][i] += R[pw*2048 + i*64 + lane];
                            accB[1][i] += R[pw*2048 + 1024 + i*64 + lane]; }
  }
  __syncthreads();
  // phase 2: accs 2,3 of give tile
  if (kh == 0){
    #pragma unroll
    for (int i=0;i<16;i++){ R[wave*2048 + i*64 + lane] = accB[2][i];
                            R[wave*2048 + 1024 + i*64 + lane] = accB[3][i]; }
  } else {
    #pragma unroll
    for (int i=0;i<16;i++){ R[wave*2048 + i*64 + lane] = accA[2][i];
                            R[wave*2048 + 1024 + i*64 + lane] = accA[3][i]; }
  }
  __syncthreads();
  if (kh == 0){
    #pragma unroll
    for (int i=0;i<16;i++){ accA[2][i] += R[pw*2048 + i*64 + lane];
                            accA[3][i] += R[pw*2048 + 1024 + i*64 + lane]; }
  } else {
    #pragma unroll
    for (int i=0;i<16;i++){ accB[2][i] += R[pw*2048 + i*64 + lane];
                            accB[3][i] += R[pw*2048 + 1024 + i*64 + lane]; }
  }

  // ---- epilogue: out = gamma*O/l + x ----
  // wave writes tile kt = 2qp+kh, channels [cd*128, +128)
  // rowsum of tile kt = RS[qp*4 + kh*2 + 0] + RS[qp*4 + kh*2 + 1]
  float g = *gptr;
  int kt = qp*2 + kh;
  int w0 = qp*4 + kh*2, w1 = w0 + 1;
  const float* xb = x + ((size_t)b*N_ + q0 + kt*32)*C_;
  float*       ob = out + ((size_t)b*N_ + q0 + kt*32)*C_;
  if (kh == 0){
    #pragma unroll
    for (int i=0;i<16;i++){
      int q = (i&3) + 8*(i>>2) + 4*h;
      float rv = 1.f / (RS[w0*32 + q] + RS[w1*32 + q]);
      #pragma unroll
      for (int c=0;c<4;c++){
        int ch = (cd*4 + c)*32 + l31;
        ob[(size_t)q*C_ + ch] = g*(accA[c][i]*rv) + xb[(size_t)q*C_ + ch];
      }
    }
  } else {
    #pragma unroll
    for (int i=0;i<16;i++){
      int q = (i&3) + 8*(i>>2) + 4*h;
      float rv = 1.f / (RS[w0*32 + q] + RS[w1*32 + q]);
      #pragma unroll
      for (int c=0;c<4;c++){
        int ch = (cd*4 + c)*32 + l31;
        ob[(size_t)q*C_ + ch] = g*(accB[c][i]*rv) + xb[(size_t)q*C_ + ch];
      }
    }
  }
#undef VPREF
#undef EXPPACK
#undef PVX
}

extern "C" void kernel_launch(void* const* d_in, const int* in_sizes, int n_in,
                              void* d_out, int out_size, void* d_ws, size_t ws_size,
                              hipStream_t stream){
  const float* x  = (const float*)d_in[0];
  const float* Wq = (const float*)d_in[1];
  const float* bq = (const float*)d_in[2];
  const float* Wk = (const float*)d_in[3];
  const float* bk = (const float*)d_in[4];
  const float* Wv = (const float*)d_in[5];
  const float* bv = (const float*)d_in[6];
  const float* gm = (const float*)d_in[7];
  float* out = (float*)d_out;
  char* ws = (char*)d_ws;
  short* WT  = (short*)ws;                               // 163840 B
  short* qws = (short*)(ws + 163840);                    // 2097152 B
  short* kws = (short*)(ws + 163840 + 2097152);          // 2097152 B
  short* vSw = (short*)(ws + 163840 + 2*2097152);        // 16777216 B

  cast_wt_kernel<<<dim3(320), dim3(256), 0, stream>>>(Wq, Wk, Wv, WT);
  proj_kernel<<<dim3(512), dim3(256), 0, stream>>>(x, WT, bq, bk, bv, qws, kws, vSw);
  flash_kernel<<<dim3(256), dim3(512), 0, stream>>>(x, qws, kws, vSw, gm, out);
}

// Round 7
// 194.384 us; speedup vs baseline: 1.2246x; 1.0553x over previous
//
#include <hip/hip_runtime.h>
#include <hip/hip_bf16.h>
#include <math.h>

#define B_ 8
#define N_ 4096
#define C_ 256
#define DQK_ 32

typedef float f32x4  __attribute__((ext_vector_type(4)));
typedef float f32x16 __attribute__((ext_vector_type(16)));
typedef short bf16x8 __attribute__((ext_vector_type(8)));
typedef short bf16x4 __attribute__((ext_vector_type(4)));

__device__ __forceinline__ short f2bf(float f){
  union { float f; unsigned u; } v; v.f = f;
  unsigned r = v.u + 0x7fffu + ((v.u >> 16) & 1u);
  return (short)(r >> 16);
}

// ---------- kernel 1: weight transpose + cast -> WT[320][256] bf16 ----------
__global__ void cast_wt_kernel(const float* __restrict__ Wq, const float* __restrict__ Wk,
                               const float* __restrict__ Wv, short* __restrict__ WT){
  int n = blockIdx.x;        // 0..319 output channel
  int k = threadIdx.x;       // 0..255 input channel
  float val;
  if (n < 32)       val = Wq[k*32 + n];
  else if (n < 64)  val = Wk[k*32 + (n-32)];
  else              val = Wv[k*256 + (n-64)];
  WT[n*256 + k] = f2bf(val);
}

// ---------- kernel 2: projections -> frag-swizzled q,k,v ----------
__global__ __launch_bounds__(256) void proj_kernel(
    const float* __restrict__ x, const short* __restrict__ WT,
    const float* __restrict__ bq, const float* __restrict__ bk, const float* __restrict__ bv,
    short* __restrict__ qws, short* __restrict__ kws, short* __restrict__ vSw){
  __shared__ __align__(16) short sX[64*264];   // 67584 B
  __shared__ __align__(16) short sT[64*72];    // 9216 B  (q cols 0..31 | k cols 32..63)
  int tid = threadIdx.x;
  int lane = tid & 63, wave = tid >> 6;
  int lane15 = lane & 15, quad = lane >> 4;
  int mbase = blockIdx.x * 64;
  int b = mbase >> 12, kvb = mbase & (N_-1);

  const float* xr = x + (size_t)mbase * C_;
  for (int i = 0; i < 8; i++){
    int s = tid + i*256;
    int row = s >> 5, cg = (s & 31) << 3;
    const f32x4* src = (const f32x4*)(xr + row*C_ + cg);
    f32x4 a = src[0], c = src[1];
    bf16x8 p;
    p[0]=f2bf(a[0]); p[1]=f2bf(a[1]); p[2]=f2bf(a[2]); p[3]=f2bf(a[3]);
    p[4]=f2bf(c[0]); p[5]=f2bf(c[1]); p[6]=f2bf(c[2]); p[7]=f2bf(c[3]);
    *(bf16x8*)(sX + row*264 + cg) = p;
  }
  __syncthreads();

  f32x4 acc[5][4];
  for (int i=0;i<5;i++) for (int mt=0;mt<4;mt++) acc[i][mt] = (f32x4)(0.f);

  for (int kc = 0; kc < 8; kc++){
    bf16x8 afr[4];
    #pragma unroll
    for (int mt=0;mt<4;mt++)
      afr[mt] = *(const bf16x8*)(sX + (mt*16+lane15)*264 + kc*32 + quad*8);
    bf16x8 bfr[5];
    #pragma unroll
    for (int i=0;i<5;i++){
      int t = i*4 + wave;
      bfr[i] = *(const bf16x8*)(WT + (size_t)(t*16+lane15)*256 + kc*32 + quad*8);
    }
    #pragma unroll
    for (int i=0;i<5;i++)
      #pragma unroll
      for (int mt=0;mt<4;mt++)
        acc[i][mt] = __builtin_amdgcn_mfma_f32_16x16x32_bf16(afr[mt], bfr[i], acc[i][mt], 0,0,0);
  }

  #pragma unroll
  for (int i=0;i<5;i++){
    int t = i*4 + wave;
    int n0 = t*16 + lane15;
    float bias = (n0 < 32) ? bq[n0] : (n0 < 64 ? bk[n0-32] : bv[n0-64]);
    if (n0 < 64){
      #pragma unroll
      for (int mt=0;mt<4;mt++)
        #pragma unroll
        for (int r=0;r<4;r++)
          sT[(mt*16 + quad*4 + r)*72 + n0] = f2bf(acc[i][mt][r] + bias);
    } else {
      int ch = n0 - 64, cht = ch >> 5, c5 = ch & 31;
      int lanep = c5 | ((quad & 1) << 5);
      int jo = (quad >> 1) * 4;
      #pragma unroll
      for (int mt=0;mt<4;mt++){
        bf16x4 pk;
        pk[0]=f2bf(acc[i][mt][0]+bias); pk[1]=f2bf(acc[i][mt][1]+bias);
        pk[2]=f2bf(acc[i][mt][2]+bias); pk[3]=f2bf(acc[i][mt][3]+bias);
        size_t off = (size_t)b*1048576 + (size_t)(kvb>>6)*16384
                   + (size_t)(mt*8 + cht)*512 + (size_t)lanep*8 + jo;
        *(bf16x4*)(vSw + off) = pk;
      }
    }
  }
  __syncthreads();

  {
    int qt = tid >> 7, p = (tid >> 6) & 1, ln = tid & 63;
    int row = qt*32 + (ln & 31);
    int dcol = p*16 + (ln >> 5)*8;
    bf16x8 vq = *(const bf16x8*)(sT + row*72 + dcol);
    bf16x8 vk = *(const bf16x8*)(sT + row*72 + 32 + dcol);
    size_t qoff = ((((size_t)b*128 + ((kvb>>5) + qt))*2 + p)*64 + ln)*8;
    *(bf16x8*)(qws + qoff) = vq;
    size_t koff = ((size_t)b*64 + (kvb>>6))*2048 + (size_t)((qt*2 + p)*64 + ln)*8;
    *(bf16x8*)(kws + koff) = vk;
  }
}

// ---------- kernel 3: flash attention + residual (v8: counted-vmcnt pipeline) ----------
// = v1's exact compute partition (wave (qt,kh): own S piece 32kv x 32q, kh-half PV,
// 8 waves, 2/SIMD — the only structure that fits 256 regs), with ONLY the sync changed:
//  * sV[4] ring (128 KB); staging issued 2 chunks ahead.
//  * per chunk: [kfn(t+1) loads; stage(t+2); QK(t)+exp(t); s_waitcnt vmcnt(4)
//    (drains stage(t+1)+kfn, leaves stage(t+2) IN FLIGHT); raw s_barrier; PV(t)].
//    No vmcnt(0) drain in the main loop (T3/T4). Issue order pinned by
//    sched_barrier(0) so the counted wait's FIFO semantics hold (rule #18).
//  * tail: dummy re-stage of chunk 63 keeps vmcnt(4) uniform; one vmcnt(0)+barrier
//    after the loop before smem is reused by the epilogue.
//  * ones-MFMA rowsum -> VALU adds + RS table (validated v5/v7): frees 20 regs
//    (arch ~110 + acc 128 = ~238 < 256; spill gate: WRITE_SIZE must be 32768 KB).
__global__ __launch_bounds__(512, 2) void flash_kernel(
    const float* __restrict__ x, const short* __restrict__ qws, const short* __restrict__ kws,
    const short* __restrict__ vSw, const float* __restrict__ gptr, float* __restrict__ out){
  __shared__ __align__(16) char smem[131072];  // sV[4][32KB]; epi: R1 64KB + RS 1KB
  int tid = threadIdx.x;
  int lane = tid & 63, wave = tid >> 6;        // wave 0..7
  int l31 = lane & 31, h = lane >> 5;
  int qt = wave >> 1, kh = wave & 1;
  int b = blockIdx.x & 7;
  int q0 = (blockIdx.x >> 3) << 7;             // 128 q-rows per block

  const short* qb = qws + (size_t)b*131072;
  const short* kb = kws + (size_t)b*131072;
  const short* vb = vSw + (size_t)b*1048576;

  int qtg = (q0 >> 5) + qt;
  bf16x8 qf0 = *(const bf16x8*)(qb + (size_t)((qtg*2+0)*64 + lane)*8);
  bf16x8 qf1 = *(const bf16x8*)(qb + (size_t)((qtg*2+1)*64 + lane)*8);

  const short* kf0p = kb + (size_t)((2*kh+0)*64 + lane)*8;
  const short* kf1p = kb + (size_t)((2*kh+1)*64 + lane)*8;

#define VPREF(CHUNK, DST) do { \
    const short* vsrc_ = vb + (size_t)(CHUNK)*16384; \
    _Pragma("unroll") \
    for (int r_=0;r_<4;r_++) \
      __builtin_amdgcn_global_load_lds( \
        (const __attribute__((address_space(1))) void*)(vsrc_ + (size_t)(r_*512+tid)*8), \
        (__attribute__((address_space(3))) void*)((DST) + (size_t)(r_*512+tid)*8), 16, 0, 0); \
  } while(0)

  // prologue: stage chunk0 -> buf0, chunk1 -> buf1; then K(0) frags (order pinned)
  VPREF(0, (short*)smem);
  VPREF(1, (short*)(smem + 32768));
  __builtin_amdgcn_sched_barrier(0);
  bf16x8 kfc0 = *(const bf16x8*)(kf0p);
  bf16x8 kfc1 = *(const bf16x8*)(kf1p);
  __builtin_amdgcn_sched_barrier(0);
  bf16x8 kfn0, kfn1;

  f32x16 acc[8];
  #pragma unroll
  for (int t=0;t<8;t++) acc[t] = (f32x16)(0.f);
  float rsO = 0.f;

  for (int it=0; it<64; it++){
    int nk = (it+1 < 64) ? (it+1) : 63;        // dummy reload at tail (uniform counts)
    int ns = (it+2 < 64) ? (it+2) : 63;        // dummy re-stage at tail

    // a: next-chunk K frags (issued FIRST -> drained by this iter's vmcnt(4))
    kfn0 = *(const bf16x8*)(kf0p + (size_t)nk*2048);
    kfn1 = *(const bf16x8*)(kf1p + (size_t)nk*2048);
    __builtin_amdgcn_sched_barrier(0);
    // b: stage chunk it+2 into ring buf (it+2)&3 (consumed by PV(it-2), certified
    //    past by the barrier of iter it-1 -> safe to overwrite)
    VPREF(ns, (short*)(smem + ((size_t)((it+2)&3))*32768));
    __builtin_amdgcn_sched_barrier(0);

    // c,d: S^T = K(t)^T Q (32kv x 32q), exp + pack + rowsum (VALU)
    f32x16 s = __builtin_amdgcn_mfma_f32_32x32x16_bf16(kfc0, qf0, (f32x16)(0.f), 0,0,0);
    s        = __builtin_amdgcn_mfma_f32_32x32x16_bf16(kfc1, qf1, s, 0,0,0);
    bf16x8 pf[2];
    #pragma unroll
    for (int g=0; g<2; g++){
      union { bf16x8 v; unsigned u[4]; } P;
      #pragma unroll
      for (int j=0;j<4;j++){
        float2 e;
        e.x = __expf(s[g*8 + 2*j]);
        e.y = __expf(s[g*8 + 2*j + 1]);
        rsO += e.x + e.y;
        __hip_bfloat162 t2 = __float22bfloat162_rn(e);
        __builtin_memcpy(&P.u[j], &t2, 4);
      }
      pf[g] = P.v;
    }

    // e,f: counted wait (drains stage(t+1)+kfn; stage(t+2) stays in flight) + raw barrier
    asm volatile("s_waitcnt vmcnt(4)" ::: "memory");
    __builtin_amdgcn_sched_barrier(0);
    __builtin_amdgcn_s_barrier();
    __builtin_amdgcn_sched_barrier(0);

    // g: PV(t) from ring buf it&3 (globally certified by iter t-1's barrier)
    {
      const short* sVc = (const short*)(smem + ((size_t)(it&3))*32768);
      #pragma unroll
      for (int g=0; g<2; g++){
        const short* base = sVc + (2*kh + g)*4096;
        #pragma unroll
        for (int cht=0; cht<8; cht++){
          bf16x8 vf = *(const bf16x8*)(base + (cht*64 + lane)*8);
          acc[cht] = __builtin_amdgcn_mfma_f32_32x32x16_bf16(pf[g], vf, acc[cht], 0,0,0);
        }
      }
    }
    kfc0 = kfn0; kfc1 = kfn1;
  }

  // drain the tail dummy stages before smem is reused, then full barrier
  asm volatile("s_waitcnt vmcnt(0)" ::: "memory");
  __builtin_amdgcn_sched_barrier(0);
  __builtin_amdgcn_s_barrier();
  __builtin_amdgcn_sched_barrier(0);

  // ---- rowsum: merge h-interleaved kv rows; publish per-(wave,q) table ----
  rsO += __shfl_xor(rsO, 32);
  float* R1 = (float*)smem;              // [wave][j(2)][i(16)][lane]  = 64 KB
  float* RS = (float*)(smem + 65536);    // [wave][32]                 = 1 KB
  int pw = wave ^ 1;
  if (lane < 32) RS[wave*32 + l31] = rsO;

  // ---- pair reduction over kv-halves (partner wave = wave^1), constant reg indices ----
  if (kh == 0){
    #pragma unroll
    for (int i=0;i<16;i++){ R1[wave*2048 + i*64 + lane] = acc[4][i];
                            R1[wave*2048 + 1024 + i*64 + lane] = acc[5][i]; }
  } else {
    #pragma unroll
    for (int i=0;i<16;i++){ R1[wave*2048 + i*64 + lane] = acc[0][i];
                            R1[wave*2048 + 1024 + i*64 + lane] = acc[1][i]; }
  }
  __syncthreads();
  if (kh == 0){
    #pragma unroll
    for (int i=0;i<16;i++){ acc[0][i] += R1[pw*2048 + i*64 + lane];
                            acc[1][i] += R1[pw*2048 + 1024 + i*64 + lane]; }
  } else {
    #pragma unroll
    for (int i=0;i<16;i++){ acc[4][i] += R1[pw*2048 + i*64 + lane];
                            acc[5][i] += R1[pw*2048 + 1024 + i*64 + lane]; }
  }
  __syncthreads();
  if (kh == 0){
    #pragma unroll
    for (int i=0;i<16;i++){ R1[wave*2048 + i*64 + lane] = acc[6][i];
                            R1[wave*2048 + 1024 + i*64 + lane] = acc[7][i]; }
  } else {
    #pragma unroll
    for (int i=0;i<16;i++){ R1[wave*2048 + i*64 + lane] = acc[2][i];
                            R1[wave*2048 + 1024 + i*64 + lane] = acc[3][i]; }
  }
  __syncthreads();
  if (kh == 0){
    #pragma unroll
    for (int i=0;i<16;i++){ acc[2][i] += R1[pw*2048 + i*64 + lane];
                            acc[3][i] += R1[pw*2048 + 1024 + i*64 + lane]; }
  } else {
    #pragma unroll
    for (int i=0;i<16;i++){ acc[6][i] += R1[pw*2048 + i*64 + lane];
                            acc[7][i] += R1[pw*2048 + 1024 + i*64 + lane]; }
  }

  // ---- epilogue: out = gamma*O/l + x ; wave owns rows [q0+32qt,+32) x ch [128kh,+128) ----
  float g = *gptr;
  const float* xb = x + ((size_t)b*N_ + q0 + qt*32)*C_;
  float*       ob = out + ((size_t)b*N_ + q0 + qt*32)*C_;
  if (kh == 0){
    #pragma unroll
    for (int i=0;i<16;i++){
      int q = (i&3) + 8*(i>>2) + 4*h;
      float rv = 1.f / (RS[(qt*2+0)*32 + q] + RS[(qt*2+1)*32 + q]);
      #pragma unroll
      for (int ct=0; ct<4; ct++){
        int ch = ct*32 + l31;
        ob[(size_t)q*C_ + ch] = g*(acc[ct][i]*rv) + xb[(size_t)q*C_ + ch];
      }
    }
  } else {
    #pragma unroll
    for (int i=0;i<16;i++){
      int q = (i&3) + 8*(i>>2) + 4*h;
      float rv = 1.f / (RS[(qt*2+0)*32 + q] + RS[(qt*2+1)*32 + q]);
      #pragma unroll
      for (int ct=0; ct<4; ct++){
        int ch = (4+ct)*32 + l31;
        ob[(size_t)q*C_ + ch] = g*(acc[4+ct][i]*rv) + xb[(size_t)q*C_ + ch];
      }
    }
  }
#undef VPREF
}

extern "C" void kernel_launch(void* const* d_in, const int* in_sizes, int n_in,
                              void* d_out, int out_size, void* d_ws, size_t ws_size,
                              hipStream_t stream){
  const float* x  = (const float*)d_in[0];
  const float* Wq = (const float*)d_in[1];
  const float* bq = (const float*)d_in[2];
  const float* Wk = (const float*)d_in[3];
  const float* bk = (const float*)d_in[4];
  const float* Wv = (const float*)d_in[5];
  const float* bv = (const float*)d_in[6];
  const float* gm = (const float*)d_in[7];
  float* out = (float*)d_out;
  char* ws = (char*)d_ws;
  short* WT  = (short*)ws;                               // 163840 B
  short* qws = (short*)(ws + 163840);                    // 2097152 B
  short* kws = (short*)(ws + 163840 + 2097152);          // 2097152 B
  short* vSw = (short*)(ws + 163840 + 2*2097152);        // 16777216 B

  cast_wt_kernel<<<dim3(320), dim3(256), 0, stream>>>(Wq, Wk, Wv, WT);
  proj_kernel<<<dim3(512), dim3(256), 0, stream>>>(x, WT, bq, bk, bv, qws, kws, vSw);
  flash_kernel<<<dim3(256), dim3(512), 0, stream>>>(x, qws, kws, vSw, gm, out);
}